// Round 1
// baseline (364.804 us; speedup 1.0000x reference)
//
#include <hip/hip_runtime.h>
#include <hip/hip_bf16.h>

typedef _Float16 f16;
typedef _Float16 f16x8 __attribute__((ext_vector_type(8)));
typedef float f32x4 __attribute__((ext_vector_type(4)));

#define SCALE 0.17677669529663687f  // 1/sqrt(32)

// workspace layout (bytes)
#define QW_OFF   0           // 768*256 f16  = 393216
#define PW_OFF   393216      // 256*256 f16  = 131072
#define QB_OFF   524288      // 768 f32      = 3072
#define BB_OFF   527360      // 8*64*64 f32  = 131072
#define AO_OFF   658432      // 2048*64*256 f16 = 67108864

__global__ __launch_bounds__(256) void prep_kernel(
    const float* __restrict__ qkv_w, const float* __restrict__ qkv_b,
    const float* __restrict__ proj_w, const float* __restrict__ bias_table,
    const int* __restrict__ rel_index,
    f16* __restrict__ qw_h, f16* __restrict__ pw_h,
    float* __restrict__ qb_s, float* __restrict__ bias_bh) {
  int i = blockIdx.x * 256 + threadIdx.x;
  if (i < 768 * 256) {
    float s = (i < 256 * 256) ? SCALE : 1.0f;   // scale q rows
    qw_h[i] = (f16)(qkv_w[i] * s);
  }
  if (i < 768) qb_s[i] = qkv_b[i] * (i < 256 ? SCALE : 1.0f);
  if (i < 256 * 256) pw_h[i] = (f16)proj_w[i];
  if (i < 8 * 64 * 64) {
    int h = i >> 12, ij = i & 4095;
    bias_bh[i] = bias_table[rel_index[ij] * 8 + h];
  }
}

// Fused: roll + window partition + QKV GEMM + attention. One block per window.
// LDS: sx [64][264] f16 (33792B) + 2 head blocks of 7424 f16 (Q[64][40], K[64][40], Vt[32][72])
__global__ __launch_bounds__(256) void winattn_kernel(
    const float* __restrict__ x, const f16* __restrict__ qw_h,
    const float* __restrict__ qb_s, const float* __restrict__ bias_bh,
    f16* __restrict__ attn_out) {

  __shared__ f16 sx[64 * 264];
  __shared__ f16 shead[2][7424];   // per head-in-pair: Q@0, K@2560, Vt@5120

  const int tid = threadIdx.x;
  const int lane = tid & 63;
  const int wv = tid >> 6;           // wave 0..3
  const int lo = lane & 15, hi = lane >> 4;

  const int win = blockIdx.x;
  const int b = win >> 10, wh = (win >> 5) & 31, ww = win & 31;

  // ---- stage A: load window (with roll by +4) into sx as fp16 ----
  {
    const int t = tid >> 2, q4 = tid & 3;
    const int r = t >> 3, c = t & 7;
    const int gr = (wh * 8 + r + 4) & 255;
    const int gc = (ww * 8 + c + 4) & 255;
    const float* src = x + (((size_t)(b * 256 + gr)) * 256 + gc) * 256;
#pragma unroll
    for (int i = 0; i < 8; ++i) {
      const int off = q4 * 8 + i * 32;
      float4 v0 = *(const float4*)(src + off);
      float4 v1 = *(const float4*)(src + off + 4);
      f16x8 hv;
      hv[0] = (f16)v0.x; hv[1] = (f16)v0.y; hv[2] = (f16)v0.z; hv[3] = (f16)v0.w;
      hv[4] = (f16)v1.x; hv[5] = (f16)v1.y; hv[6] = (f16)v1.z; hv[7] = (f16)v1.w;
      *(f16x8*)&sx[t * 264 + off] = hv;
    }
  }
  __syncthreads();

  const int hh_c = wv >> 1;   // head-in-pair for stage C
  const int mh = wv & 1;      // m-half for stage C

  for (int hp = 0; hp < 4; ++hp) {
    if (hp) __syncthreads();   // prev pass's PV reads done before overwrite
    const int h0 = hp * 2;

    // ---- stage B: QKV GEMM for heads h0, h0+1 (192 output cols) ----
    {
      int gcol[3];
#pragma unroll
      for (int j = 0; j < 3; ++j) {
        int ntg = 3 * wv + j;                       // 12 n-tiles over 4 waves
        gcol[j] = (ntg >> 2) * 256 + h0 * 32 + (ntg & 3) * 16;
      }
      f32x4 acc[3][4];
#pragma unroll
      for (int j = 0; j < 3; ++j)
#pragma unroll
        for (int mt = 0; mt < 4; ++mt) acc[j][mt] = (f32x4){0.f, 0.f, 0.f, 0.f};

#pragma unroll
      for (int kt = 0; kt < 8; ++kt) {
        f16x8 a[4];
#pragma unroll
        for (int mt = 0; mt < 4; ++mt)
          a[mt] = *(const f16x8*)&sx[(mt * 16 + lo) * 264 + kt * 32 + 8 * hi];
#pragma unroll
        for (int j = 0; j < 3; ++j) {
          f16x8 bf = *(const f16x8*)&qw_h[(size_t)(gcol[j] + lo) * 256 + kt * 32 + 8 * hi];
#pragma unroll
          for (int mt = 0; mt < 4; ++mt)
            acc[j][mt] = __builtin_amdgcn_mfma_f32_16x16x32_f16(a[mt], bf, acc[j][mt], 0, 0, 0);
        }
      }
      // epilogue: +bias, cast fp16, scatter to Q/K/Vt LDS
#pragma unroll
      for (int j = 0; j < 3; ++j) {
        const int f = gcol[j] + lo;
        const float bias = qb_s[f];
        const int seg = f >> 8;          // 0=q 1=k 2=v (wave-uniform)
        const int fin = f & 255;
        const int hsel = (fin >> 5) & 1;
        const int d = fin & 31;
        f16* hb = &shead[hsel][0];
#pragma unroll
        for (int mt = 0; mt < 4; ++mt) {
#pragma unroll
          for (int r4 = 0; r4 < 4; ++r4) {
            const int token = mt * 16 + 4 * hi + r4;
            f16 hv = (f16)(acc[j][mt][r4] + bias);
            if (seg == 0)      hb[token * 40 + d] = hv;
            else if (seg == 1) hb[2560 + token * 40 + d] = hv;
            else               hb[5120 + d * 72 + token] = hv;
          }
        }
      }
    }
    __syncthreads();

    // ---- stage C: attention for head h = h0 + hh_c; wave handles 32 query rows ----
    {
      const int h = h0 + hh_c;
      f16* hb = &shead[hh_c][0];
      const f32x4 zero = {0.f, 0.f, 0.f, 0.f};

      f16x8 kf[4];
#pragma unroll
      for (int nt = 0; nt < 4; ++nt)
        kf[nt] = *(const f16x8*)&hb[2560 + (nt * 16 + lo) * 40 + 8 * hi];

      f32x4 s[2][4];
#pragma unroll
      for (int mt2 = 0; mt2 < 2; ++mt2) {
        const int mt = mh * 2 + mt2;
        f16x8 qf = *(const f16x8*)&hb[(mt * 16 + lo) * 40 + 8 * hi];
#pragma unroll
        for (int nt = 0; nt < 4; ++nt)
          s[mt2][nt] = __builtin_amdgcn_mfma_f32_16x16x32_f16(qf, kf[nt], zero, 0, 0, 0);
      }

      // bias add
      const float* bb = bias_bh + h * 4096;
#pragma unroll
      for (int mt2 = 0; mt2 < 2; ++mt2)
#pragma unroll
        for (int nt = 0; nt < 4; ++nt)
#pragma unroll
          for (int r4 = 0; r4 < 4; ++r4) {
            const int row = (mh * 2 + mt2) * 16 + 4 * hi + r4;
            s[mt2][nt][r4] += bb[row * 64 + nt * 16 + lo];
          }

      // softmax over 64 cols: 4 per lane + reduce across 16-lane row group
      float inv[2][4];
#pragma unroll
      for (int mt2 = 0; mt2 < 2; ++mt2)
#pragma unroll
        for (int r4 = 0; r4 < 4; ++r4) {
          float m = fmaxf(fmaxf(s[mt2][0][r4], s[mt2][1][r4]),
                          fmaxf(s[mt2][2][r4], s[mt2][3][r4]));
          m = fmaxf(m, __shfl_xor(m, 1));
          m = fmaxf(m, __shfl_xor(m, 2));
          m = fmaxf(m, __shfl_xor(m, 4));
          m = fmaxf(m, __shfl_xor(m, 8));
          float sum = 0.f;
#pragma unroll
          for (int nt = 0; nt < 4; ++nt) {
            float e = __expf(s[mt2][nt][r4] - m);
            s[mt2][nt][r4] = e;
            sum += e;
          }
          sum += __shfl_xor(sum, 1);
          sum += __shfl_xor(sum, 2);
          sum += __shfl_xor(sum, 4);
          sum += __shfl_xor(sum, 8);
          inv[mt2][r4] = 1.0f / sum;
        }

      __syncthreads();   // all q/k fragment reads done before P overlays them

      f16* P = hb;       // P[64][72] overlays Q+K region
#pragma unroll
      for (int mt2 = 0; mt2 < 2; ++mt2)
#pragma unroll
        for (int nt = 0; nt < 4; ++nt)
#pragma unroll
          for (int r4 = 0; r4 < 4; ++r4) {
            const int row = (mh * 2 + mt2) * 16 + 4 * hi + r4;
            P[row * 72 + nt * 16 + lo] = (f16)(s[mt2][nt][r4] * inv[mt2][r4]);
          }

      // PV: out[64x32] = P[64x64] @ V[64x32]  (V stored transposed)
      f32x4 o[2][2];
#pragma unroll
      for (int mt2 = 0; mt2 < 2; ++mt2)
#pragma unroll
        for (int ntd = 0; ntd < 2; ++ntd) o[mt2][ntd] = zero;
#pragma unroll
      for (int kt = 0; kt < 2; ++kt) {
        f16x8 pa[2], vb2[2];
#pragma unroll
        for (int mt2 = 0; mt2 < 2; ++mt2)
          pa[mt2] = *(const f16x8*)&P[((mh * 2 + mt2) * 16 + lo) * 72 + kt * 32 + 8 * hi];
#pragma unroll
        for (int ntd = 0; ntd < 2; ++ntd)
          vb2[ntd] = *(const f16x8*)&hb[5120 + (ntd * 16 + lo) * 72 + kt * 32 + 8 * hi];
#pragma unroll
        for (int mt2 = 0; mt2 < 2; ++mt2)
#pragma unroll
          for (int ntd = 0; ntd < 2; ++ntd)
            o[mt2][ntd] = __builtin_amdgcn_mfma_f32_16x16x32_f16(pa[mt2], vb2[ntd], o[mt2][ntd], 0, 0, 0);
      }

      // store attn_out [win][token][h*32+d] fp16
      f16* ao = attn_out + (size_t)win * 64 * 256;
#pragma unroll
      for (int mt2 = 0; mt2 < 2; ++mt2)
#pragma unroll
        for (int ntd = 0; ntd < 2; ++ntd)
#pragma unroll
          for (int r4 = 0; r4 < 4; ++r4) {
            const int token = (mh * 2 + mt2) * 16 + 4 * hi + r4;
            ao[token * 256 + h * 32 + ntd * 16 + lo] = (f16)o[mt2][ntd][r4];
          }
    }
  }
}

// Proj GEMM per window + inverse roll + fp32 store
__global__ __launch_bounds__(256) void proj_kernel(
    const f16* __restrict__ attn_out, const f16* __restrict__ pw_h,
    const float* __restrict__ proj_b, float* __restrict__ out) {
  __shared__ f16 sx2[64 * 264];
  const int tid = threadIdx.x;
  const int lane = tid & 63;
  const int wv = tid >> 6;
  const int lo = lane & 15, hi = lane >> 4;
  const int win = blockIdx.x;
  const int b = win >> 10, wh = (win >> 5) & 31, ww = win & 31;

  {
    const int t = tid >> 2, q4 = tid & 3;
    const f16* src = attn_out + (size_t)win * 64 * 256 + t * 256;
#pragma unroll
    for (int i = 0; i < 8; ++i) {
      const int off = q4 * 8 + i * 32;
      *(f16x8*)&sx2[t * 264 + off] = *(const f16x8*)(src + off);
    }
  }
  __syncthreads();

  f32x4 acc[4][4];
#pragma unroll
  for (int j = 0; j < 4; ++j)
#pragma unroll
    for (int mt = 0; mt < 4; ++mt) acc[j][mt] = (f32x4){0.f, 0.f, 0.f, 0.f};

#pragma unroll
  for (int kt = 0; kt < 8; ++kt) {
    f16x8 a[4];
#pragma unroll
    for (int mt = 0; mt < 4; ++mt)
      a[mt] = *(const f16x8*)&sx2[(mt * 16 + lo) * 264 + kt * 32 + 8 * hi];
#pragma unroll
    for (int j = 0; j < 4; ++j) {
      const int n = (4 * wv + j) * 16 + lo;
      f16x8 bf = *(const f16x8*)&pw_h[(size_t)n * 256 + kt * 32 + 8 * hi];
#pragma unroll
      for (int mt = 0; mt < 4; ++mt)
        acc[j][mt] = __builtin_amdgcn_mfma_f32_16x16x32_f16(a[mt], bf, acc[j][mt], 0, 0, 0);
    }
  }

#pragma unroll
  for (int j = 0; j < 4; ++j) {
    const int n = (4 * wv + j) * 16 + lo;
    const float pb = proj_b[n];
#pragma unroll
    for (int mt = 0; mt < 4; ++mt)
#pragma unroll
      for (int r4 = 0; r4 < 4; ++r4) {
        const int token = mt * 16 + 4 * hi + r4;
        const int tr = token >> 3, tc = token & 7;
        const int gr = (wh * 8 + tr + 4) & 255;
        const int gc = (ww * 8 + tc + 4) & 255;
        out[(((size_t)(b * 256 + gr)) * 256 + gc) * 256 + n] = acc[j][mt][r4] + pb;
      }
  }
}

extern "C" void kernel_launch(void* const* d_in, const int* in_sizes, int n_in,
                              void* d_out, int out_size, void* d_ws, size_t ws_size,
                              hipStream_t stream) {
  const float* x          = (const float*)d_in[0];
  const float* qkv_w      = (const float*)d_in[1];
  const float* qkv_b      = (const float*)d_in[2];
  const float* proj_w     = (const float*)d_in[3];
  const float* proj_b     = (const float*)d_in[4];
  const float* bias_table = (const float*)d_in[5];
  const int*   rel_index  = (const int*)d_in[6];
  float* out = (float*)d_out;

  char* ws = (char*)d_ws;
  f16*   qw_h    = (f16*)(ws + QW_OFF);
  f16*   pw_h    = (f16*)(ws + PW_OFF);
  float* qb_s    = (float*)(ws + QB_OFF);
  float* bias_bh = (float*)(ws + BB_OFF);
  f16*   attn_o  = (f16*)(ws + AO_OFF);

  prep_kernel<<<768, 256, 0, stream>>>(qkv_w, qkv_b, proj_w, bias_table, rel_index,
                                       qw_h, pw_h, qb_s, bias_bh);
  winattn_kernel<<<2048, 256, 0, stream>>>(x, qw_h, qb_s, bias_bh, attn_o);
  proj_kernel<<<2048, 256, 0, stream>>>(attn_o, pw_h, proj_b, out);
}

// Round 2
// 276.350 us; speedup vs baseline: 1.3201x; 1.3201x over previous
//
#include <hip/hip_runtime.h>
#include <hip/hip_bf16.h>

typedef _Float16 f16;
typedef _Float16 f16x8 __attribute__((ext_vector_type(8)));
typedef float f32x4 __attribute__((ext_vector_type(4)));

#define SCALE 0.17677669529663687f  // 1/sqrt(32)

// workspace layout (bytes)
#define QW_OFF   0           // 768*256 f16  = 393216
#define PW_OFF   393216      // 256*256 f16  = 131072
#define QB_OFF   524288      // 768 f32      = 3072
#define BB_OFF   527360      // 8*64*64 f32  = 131072 (layout [h][col][row])
#define AO_OFF   658432      // 2048*64*256 f16 = 67108864

__global__ __launch_bounds__(256) void prep_kernel(
    const float* __restrict__ qkv_w, const float* __restrict__ qkv_b,
    const float* __restrict__ proj_w, const float* __restrict__ bias_table,
    const int* __restrict__ rel_index,
    f16* __restrict__ qw_h, f16* __restrict__ pw_h,
    float* __restrict__ qb_s, float* __restrict__ bias_bh) {
  int i = blockIdx.x * 256 + threadIdx.x;
  if (i < 768 * 256) {
    float s = (i < 256 * 256) ? SCALE : 1.0f;   // scale q rows
    qw_h[i] = (f16)(qkv_w[i] * s);
  }
  if (i < 768) qb_s[i] = qkv_b[i] * (i < 256 ? SCALE : 1.0f);
  if (i < 256 * 256) pw_h[i] = (f16)proj_w[i];
  if (i < 8 * 64 * 64) {
    // transposed layout: bias_bh[h*4096 + col*64 + row]
    int h = i >> 12, rest = i & 4095;
    int col = rest >> 6, row = rest & 63;
    bias_bh[i] = bias_table[rel_index[row * 64 + col] * 8 + h];
  }
}

// Fused: roll + window partition + QKV GEMM + attention. One block per window.
// LDS: sx [64][264] f16 (33792B) + 2 head blocks of 7424 f16 (Q[64][40], K[64][40], Vt[32][72])
__global__ __launch_bounds__(256, 2) void winattn_kernel(
    const float* __restrict__ x, const f16* __restrict__ qw_h,
    const float* __restrict__ qb_s, const float* __restrict__ bias_bh,
    f16* __restrict__ attn_out) {

  __shared__ f16 sx[64 * 264];
  __shared__ f16 shead[2][7424];   // per head-in-pair: Q@0, K@2560, Vt@5120

  const int tid = threadIdx.x;
  const int lane = tid & 63;
  const int wv = tid >> 6;           // wave 0..3
  const int lo = lane & 15, hi = lane >> 4;

  const int win = blockIdx.x;
  const int b = win >> 10, wh = (win >> 5) & 31, ww = win & 31;

  // ---- stage A: load window (with roll by +4) into sx as fp16 ----
  {
    const int t = tid >> 2, q4 = tid & 3;
    const int r = t >> 3, c = t & 7;
    const int gr = (wh * 8 + r + 4) & 255;
    const int gc = (ww * 8 + c + 4) & 255;
    const float* src = x + (((size_t)(b * 256 + gr)) * 256 + gc) * 256;
#pragma unroll
    for (int i = 0; i < 8; ++i) {
      const int off = q4 * 8 + i * 32;
      float4 v0 = *(const float4*)(src + off);
      float4 v1 = *(const float4*)(src + off + 4);
      f16x8 hv;
      hv[0] = (f16)v0.x; hv[1] = (f16)v0.y; hv[2] = (f16)v0.z; hv[3] = (f16)v0.w;
      hv[4] = (f16)v1.x; hv[5] = (f16)v1.y; hv[6] = (f16)v1.z; hv[7] = (f16)v1.w;
      *(f16x8*)&sx[t * 264 + off] = hv;
    }
  }

  const int hh_c = wv >> 1;   // head-in-pair for stage C
  const int mh = wv & 1;      // m-half for stage C

  __syncthreads();

  for (int hp = 0; hp < 4; ++hp) {
    const int h0 = hp * 2;

    // ---- B-fragment register prefetch (global/L2) — issued BEFORE the
    // pass-top barrier so the latency overlaps the barrier wait and the
    // loads pipeline as one vmcnt group instead of 24 serial latencies.
    int gcol[3];
#pragma unroll
    for (int j = 0; j < 3; ++j) {
      int ntg = 3 * wv + j;                       // 12 n-tiles over 4 waves
      gcol[j] = (ntg >> 2) * 256 + h0 * 32 + (ntg & 3) * 16;
    }
    f16x8 bfrag[3][8];
#pragma unroll
    for (int j = 0; j < 3; ++j) {
      const f16* bp = qw_h + (size_t)(gcol[j] + lo) * 256 + 8 * hi;
#pragma unroll
      for (int kt = 0; kt < 8; ++kt)
        bfrag[j][kt] = *(const f16x8*)(bp + kt * 32);
    }

    if (hp) __syncthreads();   // prev pass's PV reads done before overwrite

    // ---- stage B: QKV GEMM for heads h0, h0+1 (192 output cols) ----
    {
      f32x4 acc[3][4];
#pragma unroll
      for (int j = 0; j < 3; ++j)
#pragma unroll
        for (int mt = 0; mt < 4; ++mt) acc[j][mt] = (f32x4){0.f, 0.f, 0.f, 0.f};

#pragma unroll
      for (int kt = 0; kt < 8; ++kt) {
        f16x8 a[4];
#pragma unroll
        for (int mt = 0; mt < 4; ++mt)
          a[mt] = *(const f16x8*)&sx[(mt * 16 + lo) * 264 + kt * 32 + 8 * hi];
#pragma unroll
        for (int j = 0; j < 3; ++j) {
#pragma unroll
          for (int mt = 0; mt < 4; ++mt)
            acc[j][mt] = __builtin_amdgcn_mfma_f32_16x16x32_f16(a[mt], bfrag[j][kt], acc[j][mt], 0, 0, 0);
        }
      }
      // epilogue: +bias, cast fp16, scatter to Q/K/Vt LDS
#pragma unroll
      for (int j = 0; j < 3; ++j) {
        const int f = gcol[j] + lo;
        const float bias = qb_s[f];
        const int seg = f >> 8;          // 0=q 1=k 2=v (wave-uniform)
        const int fin = f & 255;
        const int hsel = (fin >> 5) & 1;
        const int d = fin & 31;
        f16* hb = &shead[hsel][0];
#pragma unroll
        for (int mt = 0; mt < 4; ++mt) {
#pragma unroll
          for (int r4 = 0; r4 < 4; ++r4) {
            const int token = mt * 16 + 4 * hi + r4;
            f16 hv = (f16)(acc[j][mt][r4] + bias);
            if (seg == 0)      hb[token * 40 + d] = hv;
            else if (seg == 1) hb[2560 + token * 40 + d] = hv;
            else               hb[5120 + d * 72 + token] = hv;
          }
        }
      }
    }
    __syncthreads();

    // ---- stage C: attention for head h = h0 + hh_c; wave handles 32 query rows ----
    {
      const int h = h0 + hh_c;
      f16* hb = &shead[hh_c][0];
      const f32x4 zero = {0.f, 0.f, 0.f, 0.f};

      // bias prefetch: [h][col][row] layout -> float4 along rows
      const float* bb = bias_bh + h * 4096;
      f32x4 bias_r[2][4];
#pragma unroll
      for (int mt2 = 0; mt2 < 2; ++mt2)
#pragma unroll
        for (int nt = 0; nt < 4; ++nt)
          bias_r[mt2][nt] = *(const f32x4*)&bb[(nt * 16 + lo) * 64 + (mh * 2 + mt2) * 16 + 4 * hi];

      f16x8 kf[4];
#pragma unroll
      for (int nt = 0; nt < 4; ++nt)
        kf[nt] = *(const f16x8*)&hb[2560 + (nt * 16 + lo) * 40 + 8 * hi];

      f32x4 s[2][4];
#pragma unroll
      for (int mt2 = 0; mt2 < 2; ++mt2) {
        const int mt = mh * 2 + mt2;
        f16x8 qf = *(const f16x8*)&hb[(mt * 16 + lo) * 40 + 8 * hi];
#pragma unroll
        for (int nt = 0; nt < 4; ++nt)
          s[mt2][nt] = __builtin_amdgcn_mfma_f32_16x16x32_f16(qf, kf[nt], zero, 0, 0, 0);
      }

      // bias add
#pragma unroll
      for (int mt2 = 0; mt2 < 2; ++mt2)
#pragma unroll
        for (int nt = 0; nt < 4; ++nt)
#pragma unroll
          for (int r4 = 0; r4 < 4; ++r4)
            s[mt2][nt][r4] += bias_r[mt2][nt][r4];

      // softmax over 64 cols: 4 per lane + reduce across 16-lane row group
      float inv[2][4];
#pragma unroll
      for (int mt2 = 0; mt2 < 2; ++mt2)
#pragma unroll
        for (int r4 = 0; r4 < 4; ++r4) {
          float m = fmaxf(fmaxf(s[mt2][0][r4], s[mt2][1][r4]),
                          fmaxf(s[mt2][2][r4], s[mt2][3][r4]));
          m = fmaxf(m, __shfl_xor(m, 1));
          m = fmaxf(m, __shfl_xor(m, 2));
          m = fmaxf(m, __shfl_xor(m, 4));
          m = fmaxf(m, __shfl_xor(m, 8));
          float sum = 0.f;
#pragma unroll
          for (int nt = 0; nt < 4; ++nt) {
            float e = __expf(s[mt2][nt][r4] - m);
            s[mt2][nt][r4] = e;
            sum += e;
          }
          sum += __shfl_xor(sum, 1);
          sum += __shfl_xor(sum, 2);
          sum += __shfl_xor(sum, 4);
          sum += __shfl_xor(sum, 8);
          inv[mt2][r4] = 1.0f / sum;
        }

      __syncthreads();   // all q/k fragment reads done before P overlays them

      f16* P = hb;       // P[64][72] overlays Q+K region
#pragma unroll
      for (int mt2 = 0; mt2 < 2; ++mt2)
#pragma unroll
        for (int nt = 0; nt < 4; ++nt)
#pragma unroll
          for (int r4 = 0; r4 < 4; ++r4) {
            const int row = (mh * 2 + mt2) * 16 + 4 * hi + r4;
            P[row * 72 + nt * 16 + lo] = (f16)(s[mt2][nt][r4] * inv[mt2][r4]);
          }

      // PV: out[64x32] = P[64x64] @ V[64x32]  (V stored transposed)
      f32x4 o[2][2];
#pragma unroll
      for (int mt2 = 0; mt2 < 2; ++mt2)
#pragma unroll
        for (int ntd = 0; ntd < 2; ++ntd) o[mt2][ntd] = zero;
#pragma unroll
      for (int kt = 0; kt < 2; ++kt) {
        f16x8 pa[2], vb2[2];
#pragma unroll
        for (int mt2 = 0; mt2 < 2; ++mt2)
          pa[mt2] = *(const f16x8*)&P[((mh * 2 + mt2) * 16 + lo) * 72 + kt * 32 + 8 * hi];
#pragma unroll
        for (int ntd = 0; ntd < 2; ++ntd)
          vb2[ntd] = *(const f16x8*)&hb[5120 + (ntd * 16 + lo) * 72 + kt * 32 + 8 * hi];
#pragma unroll
        for (int mt2 = 0; mt2 < 2; ++mt2)
#pragma unroll
          for (int ntd = 0; ntd < 2; ++ntd)
            o[mt2][ntd] = __builtin_amdgcn_mfma_f32_16x16x32_f16(pa[mt2], vb2[ntd], o[mt2][ntd], 0, 0, 0);
      }

      // store attn_out [win][token][h*32+d] fp16
      f16* ao = attn_out + (size_t)win * 64 * 256;
#pragma unroll
      for (int mt2 = 0; mt2 < 2; ++mt2)
#pragma unroll
        for (int ntd = 0; ntd < 2; ++ntd)
#pragma unroll
          for (int r4 = 0; r4 < 4; ++r4) {
            const int token = (mh * 2 + mt2) * 16 + 4 * hi + r4;
            ao[token * 256 + h * 32 + ntd * 16 + lo] = (f16)o[mt2][ntd][r4];
          }
    }
  }
}

// Proj GEMM per window + inverse roll + fp32 store
__global__ __launch_bounds__(256) void proj_kernel(
    const f16* __restrict__ attn_out, const f16* __restrict__ pw_h,
    const float* __restrict__ proj_b, float* __restrict__ out) {
  __shared__ f16 sx2[64 * 264];
  const int tid = threadIdx.x;
  const int lane = tid & 63;
  const int wv = tid >> 6;
  const int lo = lane & 15, hi = lane >> 4;
  const int win = blockIdx.x;
  const int b = win >> 10, wh = (win >> 5) & 31, ww = win & 31;

  {
    const int t = tid >> 2, q4 = tid & 3;
    const f16* src = attn_out + (size_t)win * 64 * 256 + t * 256;
#pragma unroll
    for (int i = 0; i < 8; ++i) {
      const int off = q4 * 8 + i * 32;
      *(f16x8*)&sx2[t * 264 + off] = *(const f16x8*)(src + off);
    }
  }
  __syncthreads();

  f32x4 acc[4][4];
#pragma unroll
  for (int j = 0; j < 4; ++j)
#pragma unroll
    for (int mt = 0; mt < 4; ++mt) acc[j][mt] = (f32x4){0.f, 0.f, 0.f, 0.f};

#pragma unroll
  for (int kt = 0; kt < 8; ++kt) {
    f16x8 a[4];
#pragma unroll
    for (int mt = 0; mt < 4; ++mt)
      a[mt] = *(const f16x8*)&sx2[(mt * 16 + lo) * 264 + kt * 32 + 8 * hi];
#pragma unroll
    for (int j = 0; j < 4; ++j) {
      const int n = (4 * wv + j) * 16 + lo;
      f16x8 bf = *(const f16x8*)&pw_h[(size_t)n * 256 + kt * 32 + 8 * hi];
#pragma unroll
      for (int mt = 0; mt < 4; ++mt)
        acc[j][mt] = __builtin_amdgcn_mfma_f32_16x16x32_f16(a[mt], bf, acc[j][mt], 0, 0, 0);
    }
  }

#pragma unroll
  for (int j = 0; j < 4; ++j) {
    const int n = (4 * wv + j) * 16 + lo;
    const float pb = proj_b[n];
#pragma unroll
    for (int mt = 0; mt < 4; ++mt)
#pragma unroll
      for (int r4 = 0; r4 < 4; ++r4) {
        const int token = mt * 16 + 4 * hi + r4;
        const int tr = token >> 3, tc = token & 7;
        const int gr = (wh * 8 + tr + 4) & 255;
        const int gc = (ww * 8 + tc + 4) & 255;
        out[(((size_t)(b * 256 + gr)) * 256 + gc) * 256 + n] = acc[j][mt][r4] + pb;
      }
  }
}

extern "C" void kernel_launch(void* const* d_in, const int* in_sizes, int n_in,
                              void* d_out, int out_size, void* d_ws, size_t ws_size,
                              hipStream_t stream) {
  const float* x          = (const float*)d_in[0];
  const float* qkv_w      = (const float*)d_in[1];
  const float* qkv_b      = (const float*)d_in[2];
  const float* proj_w     = (const float*)d_in[3];
  const float* proj_b     = (const float*)d_in[4];
  const float* bias_table = (const float*)d_in[5];
  const int*   rel_index  = (const int*)d_in[6];
  float* out = (float*)d_out;

  char* ws = (char*)d_ws;
  f16*   qw_h    = (f16*)(ws + QW_OFF);
  f16*   pw_h    = (f16*)(ws + PW_OFF);
  float* qb_s    = (float*)(ws + QB_OFF);
  float* bias_bh = (float*)(ws + BB_OFF);
  f16*   attn_o  = (f16*)(ws + AO_OFF);

  prep_kernel<<<768, 256, 0, stream>>>(qkv_w, qkv_b, proj_w, bias_table, rel_index,
                                       qw_h, pw_h, qb_s, bias_bh);
  winattn_kernel<<<2048, 256, 0, stream>>>(x, qw_h, qb_s, bias_bh, attn_o);
  proj_kernel<<<2048, 256, 0, stream>>>(attn_o, pw_h, proj_b, out);
}